// Round 1
// baseline (147.756 us; speedup 1.0000x reference)
//
#include <hip/hip_runtime.h>

#define NORG 13
#define NCH  14
#define VOX  (48 * 256 * 256)   // voxels per (batch, channel) plane = 3,145,728
#define NACC 65                 // per batch: inter1[13] sq1[13] inter2[13] sq2[13] cnt[13]
#define EPSF 1e-5f

__device__ __forceinline__ float wave_reduce(float v) {
#pragma unroll
    for (int off = 32; off; off >>= 1) v += __shfl_xor(v, off, 64);
    return v;
}

__global__ __launch_bounds__(256) void dice_partial(
    const float* __restrict__ pred1, const float* __restrict__ pred2,
    const int* __restrict__ tgt, float* __restrict__ acc_out)
{
    const int b   = blockIdx.y;
    const int nv4 = VOX / 4;
    const float4* p1 = (const float4*)(pred1 + (size_t)b * NCH * VOX);
    const float4* p2 = (const float4*)(pred2 + (size_t)b * NCH * VOX);
    const int4*   tb = (const int4*)(tgt + (size_t)b * VOX);

    float acc[NACC];
#pragma unroll
    for (int i = 0; i < NACC; ++i) acc[i] = 0.f;

    for (int v = blockIdx.x * blockDim.x + threadIdx.x; v < nv4;
         v += gridDim.x * blockDim.x) {
        const int4 t = tb[v];
#pragma unroll
        for (int o = 0; o < NORG; ++o) {
            const int ch = o + 1;
            const float4 a = p1[(size_t)ch * nv4 + v];
            const float4 c = p2[(size_t)ch * nv4 + v];
            // sum of squares (always)
            acc[13 + o] += a.x * a.x + a.y * a.y + a.z * a.z + a.w * a.w;
            acc[39 + o] += c.x * c.x + c.y * c.y + c.z * c.z + c.w * c.w;
            // masked intersection + voxel count (static index o; runtime
            // organ handled by predication, not array indexing)
            const float m0 = (t.x == ch) ? 1.f : 0.f;
            const float m1 = (t.y == ch) ? 1.f : 0.f;
            const float m2 = (t.z == ch) ? 1.f : 0.f;
            const float m3 = (t.w == ch) ? 1.f : 0.f;
            acc[o]      += m0 * a.x + m1 * a.y + m2 * a.z + m3 * a.w;
            acc[26 + o] += m0 * c.x + m1 * c.y + m2 * c.z + m3 * c.w;
            acc[52 + o] += (m0 + m1) + (m2 + m3);
        }
    }

    // block reduction: wave shuffle tree -> LDS -> one atomicAdd per slot
    __shared__ float red[4][NACC];
    const int lane = threadIdx.x & 63;
    const int wid  = threadIdx.x >> 6;
#pragma unroll
    for (int i = 0; i < NACC; ++i) {
        const float r = wave_reduce(acc[i]);
        if (lane == 0) red[wid][i] = r;
    }
    __syncthreads();
    if (threadIdx.x < NACC) {
        const float s = red[0][threadIdx.x] + red[1][threadIdx.x]
                      + red[2][threadIdx.x] + red[3][threadIdx.x];
        atomicAdd(&acc_out[b * NACC + threadIdx.x], s);
    }
}

__global__ void dice_final(const float* __restrict__ acc,
                           float* __restrict__ out, int B)
{
    if (threadIdx.x == 0 && blockIdx.x == 0) {
        float total = 0.f;
        for (int b = 0; b < B; ++b) {
            const float* a = acc + b * NACC;
            float d1 = 0.f, d2 = 0.f;
            for (int o = 0; o < NORG; ++o) {
                const float t2 = a[52 + o];
                d1 += 2.f * a[o]      / (a[13 + o] + t2 + EPSF);
                d2 += 2.f * a[26 + o] / (a[39 + o] + t2 + EPSF);
            }
            total += 2.f - (d1 + d2) / (float)NORG;
        }
        out[0] = total / (float)B;
    }
}

extern "C" void kernel_launch(void* const* d_in, const int* in_sizes, int n_in,
                              void* d_out, int out_size, void* d_ws, size_t ws_size,
                              hipStream_t stream)
{
    const float* p1  = (const float*)d_in[0];
    const float* p2  = (const float*)d_in[1];
    const int*   tgt = (const int*)d_in[2];
    float*       out = (float*)d_out;
    float*       acc = (float*)d_ws;

    const int B = in_sizes[2] / VOX;   // = 2 for the reference shapes

    // workspace is poisoned (0xAA) by the harness and never re-zeroed:
    // zero our 2*65 accumulator floats every call (async memset is
    // graph-capture safe).
    hipMemsetAsync(d_ws, 0, (size_t)B * NACC * sizeof(float), stream);

    dim3 grid(512, B);                 // 1024 blocks -> 4 blocks/CU
    dice_partial<<<grid, 256, 0, stream>>>(p1, p2, tgt, acc);
    dice_final<<<1, 64, 0, stream>>>(acc, out, B);
}